// Round 3
// baseline (391.223 us; speedup 1.0000x reference)
//
#include <hip/hip_runtime.h>

// ---------------------------------------------------------------------------
// SubtitleColorConsistencyLoss — MI355X
// Inputs (setup_inputs order):
//   d_in[0] color  f32 [8,32,512,512]
//   d_in[1] gt     f32 [8,1,512,512]
//   d_in[2] binary f32 [8,1,512,512]
//   d_in[3] labels i32 [8,512,512]
// Output: 1 f32 scalar.
//
// Structure (v2): per 2048-px stripe,
//   phase 1: read masks ONCE, pack per-pixel code (label<<2 | region) into
//            2 KB LDS; fold region/component counts in (1 count per pixel).
//   phase 2: 16 channel-pair passes read only color (global) + codes (LDS),
//            accumulate 9-segment sums in registers, butterfly-reduce,
//            LDS-atomic, then one global-atomic flush per block.
//   finalize: 1-wave kernel reproduces the reference epilogue exactly.
// Mask HBM traffic is deterministically 1x (24 MB) — no reliance on L2
// absorbing 16x re-reads. Ideal total: 280 MB ≈ 45 us at 6.3 TB/s.
// ---------------------------------------------------------------------------

#define NIMG   8
#define NCH    32
#define IMHW   (512 * 512)
#define STRIPE 2048                 // pixels per block
#define BPI    (IMHW / STRIPE)      // 128 blocks per image
#define WSN    304                  // floats per image in workspace
// workspace layout (per image, float offsets):
//   0   : regsum[3][32]   (row 0=sub, 1=scene, 2=bg)
//   96  : compsum[6][32]
//   288 : regcnt[3]       (sub, scene, bg)
//   291 : compcnt[6]
//   297 : comps2[6]       (channel-summed |f|^2 per component)
//   303 : pad

__device__ __forceinline__ float redhalf(float x) {
    // sum across each 32-lane half of the wave (xor masks <=16 stay in-half)
    x += __shfl_xor(x, 1);
    x += __shfl_xor(x, 2);
    x += __shfl_xor(x, 4);
    x += __shfl_xor(x, 8);
    x += __shfl_xor(x, 16);
    return x;
}

__device__ __forceinline__ float red64(float x) {
    x += __shfl_xor(x, 1);
    x += __shfl_xor(x, 2);
    x += __shfl_xor(x, 4);
    x += __shfl_xor(x, 8);
    x += __shfl_xor(x, 16);
    x += __shfl_xor(x, 32);
    return x;
}

__global__ __launch_bounds__(256) void scl_main(
    const float* __restrict__ color, const float* __restrict__ gt,
    const float* __restrict__ bin, const int* __restrict__ lab,
    float* __restrict__ ws)
{
    __shared__ float lds[WSN];
    __shared__ unsigned int codes[STRIPE / 4];   // 1 byte/px, packed 4/word

    const int tid = threadIdx.x;
    for (int i = tid; i < WSN; i += 256) lds[i] = 0.f;

    const int n    = blockIdx.x / BPI;
    const int pix0 = (blockIdx.x % BPI) * STRIPE;

    const float* gtn  = gt  + (size_t)n * IMHW;
    const float* binn = bin + (size_t)n * IMHW;
    const int*   labn = lab + (size_t)n * IMHW;
    const float* coln = color + (size_t)n * NCH * IMHW;

    // ---- phase 1: build codes + counts (each pixel touched exactly once) ----
    float cr0 = 0.f, cr1 = 0.f, cr2 = 0.f;
    float ck[6] = {0.f, 0.f, 0.f, 0.f, 0.f, 0.f};
#pragma unroll
    for (int j = 0; j < 2; ++j) {
        const int off = j * 1024 + (tid << 2);   // pixel offset within stripe
        const int p   = pix0 + off;
        const float4 g4 = *reinterpret_cast<const float4*>(gtn + p);
        const float4 b4 = *reinterpret_cast<const float4*>(binn + p);
        const int4   l4 = *reinterpret_cast<const int4*>(labn + p);
        const float gg[4] = {g4.x, g4.y, g4.z, g4.w};
        const float bb[4] = {b4.x, b4.y, b4.z, b4.w};
        const int   ll[4] = {l4.x, l4.y, l4.z, l4.w};
        unsigned int wrd = 0;
#pragma unroll
        for (int e = 0; e < 4; ++e) {
            const bool sub  = gg[e] > 0.5f;
            const bool text = bb[e] > 0.5f;
            const int  r    = sub ? 0 : (text ? 1 : 2);   // 0=sub 1=scene 2=bg
            const int  l    = ll[e];                      // 0..6
            wrd |= (unsigned)((l << 2) | r) << (8 * e);
            cr0 += (r == 0) ? 1.f : 0.f;
            cr1 += (r == 1) ? 1.f : 0.f;
            cr2 += (r == 2) ? 1.f : 0.f;
#pragma unroll
            for (int kk = 0; kk < 6; ++kk)
                ck[kk] += (l == kk + 1) ? 1.f : 0.f;
        }
        codes[off >> 2] = wrd;                   // word idx = j*256 + tid
    }
    __syncthreads();   // lds zeroed everywhere; codes visible to all waves

    cr0 = red64(cr0); cr1 = red64(cr1); cr2 = red64(cr2);
#pragma unroll
    for (int kk = 0; kk < 6; ++kk) ck[kk] = red64(ck[kk]);
    if ((tid & 63) == 0) {                       // one atomic set per wave
        atomicAdd(&lds[288], cr0);
        atomicAdd(&lds[289], cr1);
        atomicAdd(&lds[290], cr2);
#pragma unroll
        for (int kk = 0; kk < 6; ++kk) atomicAdd(&lds[291 + kk], ck[kk]);
    }

    // ---- phase 2: color streaming, codes from LDS ----
    const int lane = tid & 63;
    const int wv   = tid >> 6;      // wave 0..3
    const int half = lane >> 5;     // channel parity within pair
    const int l32  = lane & 31;

    for (int cpi = 0; cpi < 4; ++cpi) {
        const int cp = wv * 4 + cpi;            // channel pair 0..15 (wave-uniform)
        const int c  = cp * 2 + half;
        const float* colc = coln + (size_t)c * IMHW;

        float r0 = 0.f, r1 = 0.f, r2 = 0.f;
        float ak[6]  = {0.f, 0.f, 0.f, 0.f, 0.f, 0.f};
        float as2[6] = {0.f, 0.f, 0.f, 0.f, 0.f, 0.f};

        for (int j = 0; j < STRIPE; j += 128) {
            const int off = j + (l32 << 2);
            const float4 v4 = *reinterpret_cast<const float4*>(colc + pix0 + off);
            const unsigned int cw = codes[off >> 2];  // 32 consecutive words per half; halves broadcast
            const float vv[4] = {v4.x, v4.y, v4.z, v4.w};
#pragma unroll
            for (int e = 0; e < 4; ++e) {
                const float v = vv[e];
                const unsigned int cb = (cw >> (8 * e)) & 0xFFu;
                const int r = (int)(cb & 3u);
                const int l = (int)(cb >> 2);
                r0 += (r == 0) ? v : 0.f;
                r1 += (r == 1) ? v : 0.f;
                r2 += (r == 2) ? v : 0.f;
#pragma unroll
                for (int kk = 0; kk < 6; ++kk) {
                    const float mv = (l == kk + 1) ? v : 0.f;
                    ak[kk] += mv;
                    as2[kk] = fmaf(mv, mv, as2[kk]);
                }
            }
        }

        r0 = redhalf(r0); r1 = redhalf(r1); r2 = redhalf(r2);
#pragma unroll
        for (int kk = 0; kk < 6; ++kk) { ak[kk] = redhalf(ak[kk]); as2[kk] = redhalf(as2[kk]); }

        if (l32 == 0) {                          // lane 0 (c even) / lane 32 (c odd)
            atomicAdd(&lds[ 0 + c], r0);
            atomicAdd(&lds[32 + c], r1);
            atomicAdd(&lds[64 + c], r2);
#pragma unroll
            for (int kk = 0; kk < 6; ++kk) {
                atomicAdd(&lds[96 + kk * 32 + c], ak[kk]);
                atomicAdd(&lds[297 + kk], as2[kk]);   // channel-summed
            }
        }
    }
    __syncthreads();

    float* wsn = ws + (size_t)n * WSN;
    for (int i = tid; i < WSN; i += 256) {
        const float v = lds[i];
        if (v != 0.f) atomicAdd(&wsn[i], v);
    }
}

__global__ void scl_final(const float* __restrict__ ws, float* __restrict__ out)
{
    const int lane = threadIdx.x;               // blockDim = 64 (one wave)
    const int n = lane / 6;
    const int k = lane - n * 6;
    const bool active = lane < 48;              // 8 images x 6 components

    float t_cv = 0.f, t_intra = 0.f, t_inter = 0.f, t_inst = 0.f, t_instn = 0.f;
    float t_sbg = 0.f, t_sbgn = 0.f, t_ssc = 0.f, t_sscn = 0.f;

    if (active) {
        const float* w = ws + (size_t)n * WSN;
        const float cnt    = w[291 + k];
        const float s2     = w[297 + k];
        const float subc   = w[288];
        const float scenec = w[289];
        const float bgc    = w[290];

        float nv = 0.f;
#pragma unroll
        for (int kk = 0; kk < 6; ++kk) nv += (w[291 + kk] >= 20.f) ? 1.f : 0.f;

        const bool comp_big   = cnt >= 20.f;
        const bool item_valid = (bgc >= 20.f) && (nv >= 1.f);
        const bool cv         = comp_big && item_valid;

        const float den  = cnt + 1e-6f;
        const float dsub = subc + 1e-6f;
        const float dbg  = bgc + 1e-6f;
        const float dsc  = scenec + 1e-6f;

        float dot_mS1 = 0.f, dot_mm = 0.f, d2bg = 0.f, d2sub = 0.f;
        for (int c = 0; c < 32; ++c) {
            const float S1 = w[96 + k * 32 + c];
            const float m  = S1 / den;
            dot_mS1 = fmaf(m, S1, dot_mS1);
            dot_mm  = fmaf(m, m, dot_mm);
            const float msub = w[c] / dsub;
            const float mbg  = w[64 + c] / dbg;
            float d = m - mbg;  d2bg  = fmaf(d, d, d2bg);
            d = m - msub;       d2sub = fmaf(d, d, d2sub);
        }
        const float intra_k = (s2 - 2.f * dot_mS1 + cnt * dot_mm) / den;

        if (cv) {
            t_cv = 1.f;
            t_intra = intra_k;
            const float dd = sqrtf(fmaxf(d2bg, 1e-12f));
            const float r  = fmaxf(0.5f - dd, 0.f);
            t_inter = r * r;
        }
        const bool multi = item_valid && (nv > 1.f);
        if (cv && multi) t_inst = d2sub;

        if (k == 0) {                            // per-image terms, once
            if (multi) t_instn = nv;
            const bool bgcond = item_valid && (subc >= 20.f);
            const bool sccond = item_valid && (scenec >= 20.f) && (subc >= 20.f);
            float d2sb = 0.f, d2ss = 0.f;
            for (int c = 0; c < 32; ++c) {
                const float msub = w[c] / dsub;
                const float mbg  = w[64 + c] / dbg;
                const float msc  = w[32 + c] / dsc;
                float a = msub - mbg; d2sb = fmaf(a, a, d2sb);
                float b = msub - msc; d2ss = fmaf(b, b, d2ss);
            }
            if (bgcond) {
                const float dd = sqrtf(fmaxf(d2sb, 1e-12f));
                const float r  = fmaxf(0.5f - dd, 0.f);
                t_sbg = r * r; t_sbgn = 1.f;
            }
            if (sccond) {
                const float dd = sqrtf(fmaxf(d2ss, 1e-12f));
                const float r  = fmaxf(1.0f - dd, 0.f);   // 2*MARGIN
                t_ssc = r * r; t_sscn = 1.f;
            }
        }
    }

#define RED64(x) { x += __shfl_xor(x, 1); x += __shfl_xor(x, 2); x += __shfl_xor(x, 4); \
                   x += __shfl_xor(x, 8); x += __shfl_xor(x, 16); x += __shfl_xor(x, 32); }
    RED64(t_cv) RED64(t_intra) RED64(t_inter) RED64(t_inst) RED64(t_instn)
    RED64(t_sbg) RED64(t_sbgn) RED64(t_ssc) RED64(t_sscn)
#undef RED64

    if (lane == 0) {
        const float total = t_cv;
        auto avg = [](float s, float nn) { return nn > 0.f ? s / fmaxf(nn, 1.f) : 0.f; };
        const float loss = avg(t_intra, total)
                         + 0.4f * avg(t_inter, total)
                         + 0.1f * avg(t_inst, t_instn)
                         + 0.2f * avg(t_sbg, t_sbgn)
                         + 0.5f * avg(t_ssc, t_sscn);
        out[0] = (total > 0.f) ? loss : 0.f;
    }
}

extern "C" void kernel_launch(void* const* d_in, const int* in_sizes, int n_in,
                              void* d_out, int out_size, void* d_ws, size_t ws_size,
                              hipStream_t stream)
{
    (void)in_sizes; (void)n_in; (void)out_size; (void)ws_size;
    const float* color = (const float*)d_in[0];
    const float* gt    = (const float*)d_in[1];
    const float* bin   = (const float*)d_in[2];
    const int*   lab   = (const int*)d_in[3];
    float* ws  = (float*)d_ws;
    float* out = (float*)d_out;

    hipMemsetAsync(ws, 0, (size_t)NIMG * WSN * sizeof(float), stream);
    hipLaunchKernelGGL(scl_main, dim3(NIMG * BPI), dim3(256), 0, stream,
                       color, gt, bin, lab, ws);
    hipLaunchKernelGGL(scl_final, dim3(1), dim3(64), 0, stream, ws, out);
}